// Round 6
// baseline (568.229 us; speedup 1.0000x reference)
//
#include <hip/hip_runtime.h>

#define KERNEL_LEN 128
#define INPUT_LEN 1000000
#define PATH_NUM 10
#define L_TOTAL (INPUT_LEN + KERNEL_LEN)
#define NBLOCKS 2048
#define BLOCK_SIZE 256
#define CHUNK 4
#define ITERS 16   // DIAGNOSTIC: repeat identical work to surface kernel above
                   // the ~67us profiling floor and solve dur = F + ITERS*T.

typedef int v4i __attribute__((ext_vector_type(4)));

__global__ __launch_bounds__(BLOCK_SIZE) void dtw_spring_npath_kernel(
    const float* __restrict__ kern,
    const float* __restrict__ x,
    const int*   __restrict__ path_k,
    const int*   __restrict__ path_i,
    const int*   __restrict__ path_length,
    const int*   __restrict__ path_num,
    float*       __restrict__ out)
{
    __shared__ float k_lds[KERNEL_LEN];
    const int tid = threadIdx.x;
    if (tid < KERNEL_LEN) k_lds[tid] = kern[tid];
    __syncthreads();

    const int n = min(path_num[0], PATH_NUM);

    float acc[PATH_NUM];
    #pragma unroll
    for (int p = 0; p < PATH_NUM; ++p) acc[p] = 0.0f;

    const int start  = (blockIdx.x * BLOCK_SIZE + tid) * CHUNK;
    const int stride = NBLOCKS * BLOCK_SIZE * CHUNK;   // 2M > L: exactly 1 iter/path

    for (int it = 0; it < ITERS; ++it) {
        // forbid hoisting loads across iterations: every iter re-issues all
        // global loads (this is the thing being measured)
        asm volatile("" ::: "memory");
        #pragma unroll
        for (int p = 0; p < PATH_NUM; ++p) {
            if (p < n) {
                const int len  = path_length[p];
                const int len4 = len & ~(CHUNK - 1);
                const int* __restrict__ pk = path_k + (size_t)p * L_TOTAL;
                const int* __restrict__ pi = path_i + (size_t)p * L_TOTAL;

                float a = 0.0f;
                for (int t = start; t < len4; t += stride) {
                    const v4i ik = *reinterpret_cast<const v4i*>(pk + t);
                    const v4i ii = *reinterpret_cast<const v4i*>(pi + t);
                    const float x0 = x[(unsigned)ii[0]];
                    const float x1 = x[(unsigned)ii[1]];
                    const float x2 = x[(unsigned)ii[2]];
                    const float x3 = x[(unsigned)ii[3]];
                    const float d0 = k_lds[(unsigned)ik[0]] - x0;
                    const float d1 = k_lds[(unsigned)ik[1]] - x1;
                    const float d2 = k_lds[(unsigned)ik[2]] - x2;
                    const float d3 = k_lds[(unsigned)ik[3]] - x3;
                    a = fmaf(d0, d0, a);
                    a = fmaf(d1, d1, a);
                    a = fmaf(d2, d2, a);
                    a = fmaf(d3, d3, a);
                }
                // tail (< 4 elements): block 0 only
                if (blockIdx.x == 0) {
                    const int t = len4 + tid;
                    if (t < len) {
                        const float d = k_lds[pk[t]] - x[pi[t]];
                        a = fmaf(d, d, a);
                    }
                }
                acc[p] += a;
            }
        }
    }

    // scale the ITERS-fold accumulation back (exact to ~1e-5 rel, thr is 2%)
    #pragma unroll
    for (int p = 0; p < PATH_NUM; ++p) acc[p] *= (1.0f / ITERS);

    // per-wave reduce all paths, then cross-wave via LDS
    __shared__ float wsum[PATH_NUM][BLOCK_SIZE / 64];
    const int wave = tid >> 6;
    const int lane = tid & 63;
    #pragma unroll
    for (int p = 0; p < PATH_NUM; ++p) {
        float a = acc[p];
        #pragma unroll
        for (int off = 32; off > 0; off >>= 1)
            a += __shfl_down(a, off, 64);
        if (lane == 0) wsum[p][wave] = a;
    }
    __syncthreads();
    if (tid < PATH_NUM && tid < n) {
        const float s = wsum[tid][0] + wsum[tid][1] + wsum[tid][2] + wsum[tid][3];
        if (s != 0.0f) atomicAdd(&out[tid], s);
    }
}

extern "C" void kernel_launch(void* const* d_in, const int* in_sizes, int n_in,
                              void* d_out, int out_size, void* d_ws, size_t ws_size,
                              hipStream_t stream) {
    const float* kern        = (const float*)d_in[0];
    const float* x           = (const float*)d_in[1];
    const int*   path_k      = (const int*)d_in[2];
    const int*   path_i      = (const int*)d_in[3];
    const int*   path_length = (const int*)d_in[4];
    const int*   path_num    = (const int*)d_in[5];
    float*       out         = (float*)d_out;

    hipMemsetAsync(out, 0, (size_t)out_size * sizeof(float), stream);

    dtw_spring_npath_kernel<<<dim3(NBLOCKS), dim3(BLOCK_SIZE), 0, stream>>>(
        kern, x, path_k, path_i, path_length, path_num, out);
}

// Round 7
// 52.885 us; speedup vs baseline: 10.7447x; 10.7447x over previous
//
#include <hip/hip_runtime.h>
#include <hip/hip_bf16.h>

#define KERNEL_LEN 128
#define INPUT_LEN 1000000
#define PATH_NUM 10
#define L_TOTAL (INPUT_LEN + KERNEL_LEN)
#define NBLOCKS 2048
#define BLOCK_SIZE 256
#define CHUNK 4

typedef int v4i __attribute__((ext_vector_type(4)));

// Pre-pass: x (f32, 4MB) -> bf16 copy in d_ws (2MB). Halves the gather
// working set so it stays L2-resident against the index-stream flow.
__global__ __launch_bounds__(BLOCK_SIZE) void conv_x_bf16(
    const float* __restrict__ x, __hip_bfloat16* __restrict__ xb)
{
    const int i0 = blockIdx.x * BLOCK_SIZE + threadIdx.x;
    const int stride = gridDim.x * BLOCK_SIZE;
    for (int i = i0; i < INPUT_LEN; i += stride)
        xb[i] = __float2bfloat16(x[i]);
}

__global__ __launch_bounds__(BLOCK_SIZE) void dtw_spring_npath_kernel(
    const float* __restrict__ kern,
    const __hip_bfloat16* __restrict__ xb,
    const int*   __restrict__ path_k,
    const int*   __restrict__ path_i,
    const int*   __restrict__ path_length,
    const int*   __restrict__ path_num,
    float*       __restrict__ out)
{
    __shared__ float k_lds[KERNEL_LEN];
    const int tid = threadIdx.x;
    if (tid < KERNEL_LEN) k_lds[tid] = kern[tid];
    __syncthreads();

    const int n = min(path_num[0], PATH_NUM);

    float acc[PATH_NUM];
    #pragma unroll
    for (int p = 0; p < PATH_NUM; ++p) acc[p] = 0.0f;

    const int start  = (blockIdx.x * BLOCK_SIZE + tid) * CHUNK;
    const int stride = NBLOCKS * BLOCK_SIZE * CHUNK;   // 2M > L: exactly 1 iter/path

    #pragma unroll
    for (int p = 0; p < PATH_NUM; ++p) {
        if (p < n) {                                   // uniform guard
            const int len  = path_length[p];
            const int len4 = len & ~(CHUNK - 1);
            const int* __restrict__ pk = path_k + (size_t)p * L_TOTAL;
            const int* __restrict__ pi = path_i + (size_t)p * L_TOTAL;

            float a = 0.0f;
            for (int t = start; t < len4; t += stride) {
                const v4i ik = *reinterpret_cast<const v4i*>(pk + t);
                const v4i ii = *reinterpret_cast<const v4i*>(pi + t);
                const float x0 = __bfloat162float(xb[(unsigned)ii[0]]);
                const float x1 = __bfloat162float(xb[(unsigned)ii[1]]);
                const float x2 = __bfloat162float(xb[(unsigned)ii[2]]);
                const float x3 = __bfloat162float(xb[(unsigned)ii[3]]);
                const float d0 = k_lds[(unsigned)ik[0]] - x0;
                const float d1 = k_lds[(unsigned)ik[1]] - x1;
                const float d2 = k_lds[(unsigned)ik[2]] - x2;
                const float d3 = k_lds[(unsigned)ik[3]] - x3;
                a = fmaf(d0, d0, a);
                a = fmaf(d1, d1, a);
                a = fmaf(d2, d2, a);
                a = fmaf(d3, d3, a);
            }
            // tail (< 4 elements): block 0 only
            if (blockIdx.x == 0) {
                const int t = len4 + tid;
                if (t < len) {
                    const float d = k_lds[pk[t]] - __bfloat162float(xb[pi[t]]);
                    a = fmaf(d, d, a);
                }
            }
            acc[p] = a;
        }
    }

    // per-wave reduce all paths, then cross-wave via LDS
    __shared__ float wsum[PATH_NUM][BLOCK_SIZE / 64];
    const int wave = tid >> 6;
    const int lane = tid & 63;
    #pragma unroll
    for (int p = 0; p < PATH_NUM; ++p) {
        float a = acc[p];
        #pragma unroll
        for (int off = 32; off > 0; off >>= 1)
            a += __shfl_down(a, off, 64);
        if (lane == 0) wsum[p][wave] = a;
    }
    __syncthreads();
    if (tid < PATH_NUM && tid < n) {
        const float s = wsum[tid][0] + wsum[tid][1] + wsum[tid][2] + wsum[tid][3];
        if (s != 0.0f) atomicAdd(&out[tid], s);
    }
}

extern "C" void kernel_launch(void* const* d_in, const int* in_sizes, int n_in,
                              void* d_out, int out_size, void* d_ws, size_t ws_size,
                              hipStream_t stream) {
    const float* kern        = (const float*)d_in[0];
    const float* x           = (const float*)d_in[1];
    const int*   path_k      = (const int*)d_in[2];
    const int*   path_i      = (const int*)d_in[3];
    const int*   path_length = (const int*)d_in[4];
    const int*   path_num    = (const int*)d_in[5];
    float*       out         = (float*)d_out;
    __hip_bfloat16* xb       = (__hip_bfloat16*)d_ws;   // 2MB << ws_size

    hipMemsetAsync(out, 0, (size_t)out_size * sizeof(float), stream);
    conv_x_bf16<<<dim3(512), dim3(BLOCK_SIZE), 0, stream>>>(x, xb);
    dtw_spring_npath_kernel<<<dim3(NBLOCKS), dim3(BLOCK_SIZE), 0, stream>>>(
        kern, xb, path_k, path_i, path_length, path_num, out);
}

// Round 8
// 52.449 us; speedup vs baseline: 10.8339x; 1.0083x over previous
//
#include <hip/hip_runtime.h>

#define KERNEL_LEN 128
#define INPUT_LEN 1000000
#define PATH_NUM 10
#define L_TOTAL (INPUT_LEN + KERNEL_LEN)   // 1000128
#define BLOCK_SIZE 256
#define CHUNK 4
#define CHUNK_ELEMS (BLOCK_SIZE * CHUNK)   // 1024
#define NWIN 977                            // ceil(L_TOTAL / CHUNK_ELEMS)
#define WIN_ROT 98                          // ~NWIN/PATH_NUM: stratify windows

typedef int v4i __attribute__((ext_vector_type(4)));

__global__ __launch_bounds__(BLOCK_SIZE) void dtw_spring_npath_kernel(
    const float* __restrict__ kern,
    const float* __restrict__ x,
    const int*   __restrict__ path_k,
    const int*   __restrict__ path_i,
    const int*   __restrict__ path_length,
    const int*   __restrict__ path_num,
    float*       __restrict__ out)
{
    __shared__ float k_lds[KERNEL_LEN];
    const int tid = threadIdx.x;
    if (tid < KERNEL_LEN) k_lds[tid] = kern[tid];
    __syncthreads();

    const int n   = min(path_num[0], PATH_NUM);
    const int bid = blockIdx.x;

    float acc[PATH_NUM];
    #pragma unroll
    for (int p = 0; p < PATH_NUM; ++p) acc[p] = 0.0f;

    // Each block owns ONE window per path, rotated by p*WIN_ROT so the
    // block's windows are spread across [0, NWIN) -> per-block active-chunk
    // count is ~Sigma len_p / L ~= 4.8 with low variance (fixes the skew
    // where low-bid blocks did 10 chunks and high-bid blocks did 0).
    #pragma unroll
    for (int p = 0; p < PATH_NUM; ++p) {
        if (p < n) {
            const int len = path_length[p];            // scalar, L1-cached
            int w = bid + p * WIN_ROT;
            if (w >= NWIN) w -= NWIN;                  // bid+9*98 < 2*NWIN
            if (w * CHUNK_ELEMS < len) {               // block-uniform branch
                const int t0 = w * CHUNK_ELEMS + tid * CHUNK;
                const int tl = min(t0, L_TOTAL - CHUNK);  // row-end clamp (w=976)
                const int* __restrict__ pk = path_k + (size_t)p * L_TOTAL;
                const int* __restrict__ pi = path_i + (size_t)p * L_TOTAL;
                const v4i ik = *reinterpret_cast<const v4i*>(pk + tl);
                const v4i ii = *reinterpret_cast<const v4i*>(pi + tl);
                // gathers unconditional within an active chunk (indices are
                // valid in [0,INPUT_LEN) even past len; clamped lanes load
                // duplicate-but-valid indices) -- only the FMA is masked.
                const float x0 = x[(unsigned)ii[0]];
                const float x1 = x[(unsigned)ii[1]];
                const float x2 = x[(unsigned)ii[2]];
                const float x3 = x[(unsigned)ii[3]];
                const float d0 = k_lds[(unsigned)ik[0]] - x0;
                const float d1 = k_lds[(unsigned)ik[1]] - x1;
                const float d2 = k_lds[(unsigned)ik[2]] - x2;
                const float d3 = k_lds[(unsigned)ik[3]] - x3;
                float a = 0.0f;
                a = fmaf(d0, d0, a); a = (t0 + 0 < len) ? a : 0.0f;  // j=0
                float b1 = fmaf(d1, d1, 0.0f); a += (t0 + 1 < len) ? b1 : 0.0f;
                float b2 = fmaf(d2, d2, 0.0f); a += (t0 + 2 < len) ? b2 : 0.0f;
                float b3 = fmaf(d3, d3, 0.0f); a += (t0 + 3 < len) ? b3 : 0.0f;
                acc[p] += a;
            }
        }
    }

    // per-wave reduce all paths, then cross-wave via LDS
    __shared__ float wsum[PATH_NUM][BLOCK_SIZE / 64];
    const int wave = tid >> 6;
    const int lane = tid & 63;
    #pragma unroll
    for (int p = 0; p < PATH_NUM; ++p) {
        float a = acc[p];
        #pragma unroll
        for (int off = 32; off > 0; off >>= 1)
            a += __shfl_down(a, off, 64);
        if (lane == 0) wsum[p][wave] = a;
    }
    __syncthreads();
    if (tid < PATH_NUM && tid < n) {
        const float s = wsum[tid][0] + wsum[tid][1] + wsum[tid][2] + wsum[tid][3];
        if (s != 0.0f) atomicAdd(&out[tid], s);
    }
}

extern "C" void kernel_launch(void* const* d_in, const int* in_sizes, int n_in,
                              void* d_out, int out_size, void* d_ws, size_t ws_size,
                              hipStream_t stream) {
    const float* kern        = (const float*)d_in[0];
    const float* x           = (const float*)d_in[1];
    const int*   path_k      = (const int*)d_in[2];
    const int*   path_i      = (const int*)d_in[3];
    const int*   path_length = (const int*)d_in[4];
    const int*   path_num    = (const int*)d_in[5];
    float*       out         = (float*)d_out;

    hipMemsetAsync(out, 0, (size_t)out_size * sizeof(float), stream);

    dtw_spring_npath_kernel<<<dim3(NWIN), dim3(BLOCK_SIZE), 0, stream>>>(
        kern, x, path_k, path_i, path_length, path_num, out);
}